// Round 2
// baseline (155.254 us; speedup 1.0000x reference)
//
#include <hip/hip_runtime.h>

// Canvas geometry from the reference.
#define CANVAS_H 6144
#define CANVAS_W 6144
#define BLOCK 256
#define PER_THREAD 16                       // pixels per thread = 4 float4 quads
#define WAVE_PX (64 * PER_THREAD)           // 1024 contiguous pixels per wave
#define BLOCK_PX (BLOCK * PER_THREAD)       // 4096 contiguous pixels per block

// Native clang vector type: __builtin_nontemporal_store requires a scalar /
// native-vector pointee (HIP's float4 is a class and is rejected).
typedef float f32x4 __attribute__((ext_vector_type(4)));

// Fewer, fatter waves: the 4 px/thread version (147K waves, one store per
// wave) ran at ~2.6 TB/s write BW — wave-launch grain, not BW, was the limit.
// 16 px/thread cuts waves 4x; each of the 4 stores per thread is still a
// fully-coalesced 1 KiB wave-write via the lane-quad interleave below.
__global__ __launch_bounds__(BLOCK) void
LineRaster2d_kernel(const float* __restrict__ p0g,
                    const float* __restrict__ p1g,
                    float* __restrict__ out) {
    const int lane   = threadIdx.x & 63;
    const int waveId = blockIdx.x * (BLOCK / 64) + (threadIdx.x >> 6);
    const int wbase  = waveId * WAVE_PX;    // wave's first pixel (fits int32)

    // 6144 % 1024 == 0, so a wave's 1024 pixels always share one row -> x is
    // wave-uniform.
    const int x  = (int)((unsigned)wbase / CANVAS_W);   // magic-mul, no divide
    const int yw = wbase - x * CANVAS_W;

    // Uniform setup: endpoints in pixel coords.
    const float p0x = p0g[0] * (float)CANVAS_H;
    const float p0y = p0g[1] * (float)CANVAS_W;
    const float dx  = p1g[0] * (float)CANVAS_H - p0x;
    const float dy  = p1g[1] * (float)CANVAS_W - p0y;
    // v_rcp_f32: ~1 ulp, far within the 2e-2 absmax budget.
    const float inv_len_sq = __builtin_amdgcn_rcpf(dx * dx + dy * dy);

    const float px    = (float)x - p0x;
    const float px_dx = px * dx;

    // Lane-quad interleave: store instruction j covers pixels
    // [wbase + j*256, wbase + j*256 + 256) — 64 lanes x 16 B contiguous.
    #pragma unroll
    for (int j = 0; j < PER_THREAD / 4; ++j) {
        const int y0 = yw + j * 256 + lane * 4;   // this quad's first pixel

        f32x4 r = (f32x4)(0.0f, 0.0f, 0.0f, 0.0f);

        // Conservative reject per quad: distance from quad center (x, y0+1.5)
        // to the segment. Point-to-segment distance is 1-Lipschitz in the
        // query point and the farthest pixel center is 1.5 away, so
        // dist_center >= 2.5 implies all four pixels output 0. Test against
        // 3.0 (squared: 9) for 0.5 of fp-rounding margin.
        const float pyc = ((float)y0 + 1.5f) - p0y;
        float tc = (px_dx + pyc * dy) * inv_len_sq;
        tc = fminf(fmaxf(tc, 0.0f), 1.0f);
        const float ecx = px - tc * dx;
        const float ecy = pyc - tc * dy;

        if (ecx * ecx + ecy * ecy < 9.0f) {       // ~0.1% of quads -> execz
            float py, t, ex, ey, dist;

            py = (float)(y0 + 0) - p0y;
            t  = fminf(fmaxf((px_dx + py * dy) * inv_len_sq, 0.0f), 1.0f);
            ex = px - t * dx;  ey = py - t * dy;
            dist = __builtin_amdgcn_sqrtf(ex * ex + ey * ey);
            r.x = (dist < 1.0f) ? (1.0f - dist) : 0.0f;

            py = (float)(y0 + 1) - p0y;
            t  = fminf(fmaxf((px_dx + py * dy) * inv_len_sq, 0.0f), 1.0f);
            ex = px - t * dx;  ey = py - t * dy;
            dist = __builtin_amdgcn_sqrtf(ex * ex + ey * ey);
            r.y = (dist < 1.0f) ? (1.0f - dist) : 0.0f;

            py = (float)(y0 + 2) - p0y;
            t  = fminf(fmaxf((px_dx + py * dy) * inv_len_sq, 0.0f), 1.0f);
            ex = px - t * dx;  ey = py - t * dy;
            dist = __builtin_amdgcn_sqrtf(ex * ex + ey * ey);
            r.z = (dist < 1.0f) ? (1.0f - dist) : 0.0f;

            py = (float)(y0 + 3) - p0y;
            t  = fminf(fmaxf((px_dx + py * dy) * inv_len_sq, 0.0f), 1.0f);
            ex = px - t * dx;  ey = py - t * dy;
            dist = __builtin_amdgcn_sqrtf(ex * ex + ey * ey);
            r.w = (dist < 1.0f) ? (1.0f - dist) : 0.0f;
        }

        // Pure streaming write, no reuse: nontemporal to skip L2 allocate.
        __builtin_nontemporal_store(
            r, reinterpret_cast<f32x4*>(out + wbase + j * 256 + lane * 4));
    }
}

extern "C" void kernel_launch(void* const* d_in, const int* in_sizes, int n_in,
                              void* d_out, int out_size, void* d_ws, size_t ws_size,
                              hipStream_t stream) {
    const float* p0 = (const float*)d_in[0];
    const float* p1 = (const float*)d_in[1];
    float* out = (float*)d_out;

    const long long n_pix = (long long)CANVAS_H * CANVAS_W;   // == out_size/4
    const int n_blocks = (int)(n_pix / BLOCK_PX);             // 9,216

    LineRaster2d_kernel<<<n_blocks, BLOCK, 0, stream>>>(p0, p1, out);
}

// Round 3
// 153.060 us; speedup vs baseline: 1.0143x; 1.0143x over previous
//
#include <hip/hip_runtime.h>

// Canvas geometry from the reference.
#define CANVAS_H 6144
#define CANVAS_W 6144
#define BLOCK 256
#define GRID 2048                              // 8 WGs/CU x 256 CUs: persistent
#define NTHREADS (GRID * BLOCK)                // 524,288
#define NQUADS ((CANVAS_H * CANVAS_W) / 4)     // 9,437,184 = 18 * NTHREADS
#define STEPS (NQUADS / NTHREADS)              // 18 quads per thread, no tail
// Per-step pixel advance = NTHREADS*4 = 2,097,152 = 341*6144 + 2048.
#define ROW_ADV 341
#define COL_ADV 2048

// Native clang vector type -> single global_store_dwordx4.
typedef float f32x4 __attribute__((ext_vector_type(4)));

// Fill-mimic experiment: __amd_rocclr_fillBufferAligned achieves 6.6 TB/s on
// this exact buffer in this exact graph with a persistent grid-stride loop.
// Our transient-wave versions (147K and 36.9K one-shot waves) both pinned at
// ~2.6 TB/s. This version copies the fill's launch shape: 8 WG/CU alive for
// the whole stream, each wave issuing 18 coalesced 1 KiB stores back-to-back
// (deep outstanding-store queue, no per-wave vmcnt drain every few stores,
// no wave churn). Compute per quad is unchanged (measured-negligible).
__global__ __launch_bounds__(BLOCK) void
LineRaster2d_kernel(const float* __restrict__ p0g,
                    const float* __restrict__ p1g,
                    float* __restrict__ out) {
    const int tid = blockIdx.x * BLOCK + threadIdx.x;

    // Uniform setup: endpoints in pixel coords.
    const float p0x = p0g[0] * (float)CANVAS_H;
    const float p0y = p0g[1] * (float)CANVAS_W;
    const float dx  = p1g[0] * (float)CANVAS_H - p0x;
    const float dy  = p1g[1] * (float)CANVAS_W - p0y;
    // v_rcp_f32: ~1 ulp, far within the 2e-2 absmax budget.
    const float inv_len_sq = __builtin_amdgcn_rcpf(dx * dx + dy * dy);

    // Quad-index state, advanced by wrap-increment (one magic-mul divide total).
    int q   = tid;                                     // quad index
    const int px0 = q * 4;
    int x   = (int)((unsigned)px0 / CANVAS_W);         // magic-mul, no HW divide
    int y0  = px0 - x * CANVAS_W;                      // quad's first pixel col

    for (int s = 0; s < STEPS; ++s) {
        f32x4 r = (f32x4)(0.0f, 0.0f, 0.0f, 0.0f);

        const float px    = (float)x - p0x;
        const float px_dx = px * dx;

        // Conservative reject per quad: distance from quad center (x, y0+1.5)
        // to the segment. Point-to-segment distance is 1-Lipschitz in the
        // query point; farthest pixel center is 1.5 away, so dist_center >=
        // 2.5 implies all four pixels are 0. Test 3.0 (sq: 9) for fp margin.
        const float pyc = ((float)y0 + 1.5f) - p0y;
        float tc = (px_dx + pyc * dy) * inv_len_sq;
        tc = fminf(fmaxf(tc, 0.0f), 1.0f);
        const float ecx = px - tc * dx;
        const float ecy = pyc - tc * dy;

        if (ecx * ecx + ecy * ecy < 9.0f) {            // ~0.1% taken -> execz
            float py, t, ex, ey, dist;

            py = (float)(y0 + 0) - p0y;
            t  = fminf(fmaxf((px_dx + py * dy) * inv_len_sq, 0.0f), 1.0f);
            ex = px - t * dx;  ey = py - t * dy;
            dist = __builtin_amdgcn_sqrtf(ex * ex + ey * ey);
            r.x = (dist < 1.0f) ? (1.0f - dist) : 0.0f;

            py = (float)(y0 + 1) - p0y;
            t  = fminf(fmaxf((px_dx + py * dy) * inv_len_sq, 0.0f), 1.0f);
            ex = px - t * dx;  ey = py - t * dy;
            dist = __builtin_amdgcn_sqrtf(ex * ex + ey * ey);
            r.y = (dist < 1.0f) ? (1.0f - dist) : 0.0f;

            py = (float)(y0 + 2) - p0y;
            t  = fminf(fmaxf((px_dx + py * dy) * inv_len_sq, 0.0f), 1.0f);
            ex = px - t * dx;  ey = py - t * dy;
            dist = __builtin_amdgcn_sqrtf(ex * ex + ey * ey);
            r.z = (dist < 1.0f) ? (1.0f - dist) : 0.0f;

            py = (float)(y0 + 3) - p0y;
            t  = fminf(fmaxf((px_dx + py * dy) * inv_len_sq, 0.0f), 1.0f);
            ex = px - t * dx;  ey = py - t * dy;
            dist = __builtin_amdgcn_sqrtf(ex * ex + ey * ey);
            r.w = (dist < 1.0f) ? (1.0f - dist) : 0.0f;
        }

        // Plain coalesced 16B store (matches the fill; NT made no difference).
        *reinterpret_cast<f32x4*>(out + (size_t)q * 4) = r;

        // Advance one grid-stride: 341 rows + 2048 cols (per-lane wrap).
        q  += NTHREADS;
        x  += ROW_ADV;
        y0 += COL_ADV;
        if (y0 >= CANVAS_W) { y0 -= CANVAS_W; x += 1; }
    }
}

extern "C" void kernel_launch(void* const* d_in, const int* in_sizes, int n_in,
                              void* d_out, int out_size, void* d_ws, size_t ws_size,
                              hipStream_t stream) {
    const float* p0 = (const float*)d_in[0];
    const float* p1 = (const float*)d_in[1];
    float* out = (float*)d_out;

    LineRaster2d_kernel<<<GRID, BLOCK, 0, stream>>>(p0, p1, out);
}

// Round 4
// 149.657 us; speedup vs baseline: 1.0374x; 1.0227x over previous
//
#include <hip/hip_runtime.h>

// Canvas geometry from the reference.
#define CANVAS_H 6144
#define CANVAS_W 6144
#define BLOCK 256

// FINAL / revert-to-best. Session findings (rounds 0-3):
//  - The timed graph = 604 MB re-poison fill (91-97 us @ 6.6 TB/s, harness-
//    fixed) + dozens of tiny reset dispatches (~30 us, harness-fixed) + this
//    kernel's mandatory 151 MB full-canvas write (floor ~23 us @ the fill-
//    demonstrated 6.6 TB/s write ceiling).
//  - Three orthogonal launch shapes (147K one-store waves; 36.9K four-store
//    waves + nontemporal; persistent 8-WG/CU grid-stride fill-mimic) were all
//    null deltas on residual-over-fill (57/58/61 us) -> the kernel is already
//    at its write floor; the residual is harness overhead.
//  - Re-poison semantics force writing every pixel (can't skip zeros).
// This is the best-measured variant (148.3 us total).
__global__ __launch_bounds__(BLOCK) void
LineRaster2d_kernel(const float* __restrict__ p0g,
                    const float* __restrict__ p1g,
                    float* __restrict__ out) {
    const int tid  = blockIdx.x * BLOCK + threadIdx.x;
    const int base = tid * 4;                    // fits in int32 (37.7M < 2^31)

    // W % 4 == 0, so the 4 pixels of one thread always share a row.
    const int x  = (int)((unsigned)base / CANVAS_W);   // magic-mul, no HW divide
    const int y0 = base - x * CANVAS_W;

    // Uniform setup (scalar loads / SALU): endpoints in pixel coords.
    const float p0x = p0g[0] * (float)CANVAS_H;
    const float p0y = p0g[1] * (float)CANVAS_W;
    const float dx  = p1g[0] * (float)CANVAS_H - p0x;
    const float dy  = p1g[1] * (float)CANVAS_W - p0y;
    // v_rcp_f32: ~1 ulp, far within the 2e-2 absmax budget.
    const float inv_len_sq = __builtin_amdgcn_rcpf(dx * dx + dy * dy);

    const float px = (float)x - p0x;

    // ---- Conservative reject: distance from group center (x, y0+1.5) to the
    // segment. Point-to-segment distance is 1-Lipschitz in the query point and
    // the farthest pixel center is 1.5 away, so dist_center >= 2.5 implies all
    // four pixels have dist >= 1 (output 0). Test against 3.0 (squared: 9) for
    // 0.5 of fp-rounding margin.
    const float pyc = ((float)y0 + 1.5f) - p0y;
    float tc = (px * dx + pyc * dy) * inv_len_sq;
    tc = fminf(fmaxf(tc, 0.0f), 1.0f);
    const float ecx = px - tc * dx;
    const float ecy = pyc - tc * dy;
    const float d2c = ecx * ecx + ecy * ecy;

    float4 r = make_float4(0.0f, 0.0f, 0.0f, 0.0f);
    if (d2c < 9.0f) {                 // taken by ~0.1% of waves -> execz skip
        const float px_dx = px * dx;
        float py, t, ex, ey, dist;

        py = (float)(y0 + 0) - p0y;
        t  = fminf(fmaxf((px_dx + py * dy) * inv_len_sq, 0.0f), 1.0f);
        ex = px - t * dx;  ey = py - t * dy;
        dist = __builtin_amdgcn_sqrtf(ex * ex + ey * ey);
        r.x = (dist < 1.0f) ? (1.0f - dist) : 0.0f;

        py = (float)(y0 + 1) - p0y;
        t  = fminf(fmaxf((px_dx + py * dy) * inv_len_sq, 0.0f), 1.0f);
        ex = px - t * dx;  ey = py - t * dy;
        dist = __builtin_amdgcn_sqrtf(ex * ex + ey * ey);
        r.y = (dist < 1.0f) ? (1.0f - dist) : 0.0f;

        py = (float)(y0 + 2) - p0y;
        t  = fminf(fmaxf((px_dx + py * dy) * inv_len_sq, 0.0f), 1.0f);
        ex = px - t * dx;  ey = py - t * dy;
        dist = __builtin_amdgcn_sqrtf(ex * ex + ey * ey);
        r.z = (dist < 1.0f) ? (1.0f - dist) : 0.0f;

        py = (float)(y0 + 3) - p0y;
        t  = fminf(fmaxf((px_dx + py * dy) * inv_len_sq, 0.0f), 1.0f);
        ex = px - t * dx;  ey = py - t * dy;
        dist = __builtin_amdgcn_sqrtf(ex * ex + ey * ey);
        r.w = (dist < 1.0f) ? (1.0f - dist) : 0.0f;
    }

    // One fully-coalesced 16B store per lane: 1 KB per wave per instruction.
    *reinterpret_cast<float4*>(out + base) = r;
}

extern "C" void kernel_launch(void* const* d_in, const int* in_sizes, int n_in,
                              void* d_out, int out_size, void* d_ws, size_t ws_size,
                              hipStream_t stream) {
    const float* p0 = (const float*)d_in[0];
    const float* p1 = (const float*)d_in[1];
    float* out = (float*)d_out;

    const long long n_pix = (long long)CANVAS_H * CANVAS_W;   // == out_size
    const int n_blocks = (int)(n_pix / (4 * BLOCK));          // 36,864

    LineRaster2d_kernel<<<n_blocks, BLOCK, 0, stream>>>(p0, p1, out);
}